// Round 17
// baseline (37.901 us; speedup 1.0000x reference)
//
#include <hip/hip_runtime.h>

// Problem dims (fixed by the reference)
#define BB 2
#define LL 1024
#define DI 1536
#define DS 16
#define TPB 256
#define NC 64
#define CL (LL / NC)   // 16

#define LOG2E 1.44269504088896340736f

__device__ __forceinline__ float exp2_fast(float x) { return __builtin_amdgcn_exp2f(x); }

// bf16 pack/unpack (RNE rounding)
__device__ __forceinline__ unsigned int f2bf_round(float f) {
    unsigned int u = __float_as_uint(f);
    return (u + 0x7FFFu + ((u >> 16) & 1u)) >> 16;
}
__device__ __forceinline__ unsigned int pack2(float lo, float hi) {
    return f2bf_round(lo) | (f2bf_round(hi) << 16);
}
__device__ __forceinline__ float bf_lo(unsigned int w) { return __uint_as_float(w << 16); }
__device__ __forceinline__ float bf_hi(unsigned int w) { return __uint_as_float(w & 0xFFFF0000u); }

// ---------------------------------------------------------------------------
// Pass 1: thread <-> (b, d, chunk); all 16 n-states in registers.
// Order: stage B -> barrier -> dt/uu burst -> A load (in flight) -> compute.
// Stores: sdt (f32), Bacc[16] bf16 (2x uint4), and packed (dt,uu) bf16x2
// for ss2 (same-XCD L2-local forward; ss2 never re-reads u/delta).
// Layouts: sdt [c][b][d], bsum [c][b][d][n], dtuu [c][b][i][d]
// ---------------------------------------------------------------------------
__global__ __launch_bounds__(TPB) void ss1(
    const float* __restrict__ u, const float* __restrict__ delta,
    const float* __restrict__ A, const float* __restrict__ Bm,
    float* __restrict__ sdt_out, unsigned short* __restrict__ bsum,
    unsigned int* __restrict__ dtuu_out)
{
    __shared__ float bsh[CL * DS];

    const int tid = threadIdx.x;
    const int d = blockIdx.x * TPB + tid;
    const int c = blockIdx.y;
    const int b = blockIdx.z;

    const size_t bl0 = (size_t)b * LL + (size_t)c * CL;

    // Stage B tile; barrier drains only this op.
    {
        const float* __restrict__ bp0 = Bm + bl0 * DS;
        if (tid < CL * DS) bsh[tid] = bp0[tid];
    }
    __syncthreads();

    // dt/uu burst (coalesced 256B/wave per row).
    const float* __restrict__ dp = delta + bl0 * DI + d;
    const float* __restrict__ up = u     + bl0 * DI + d;

    float dt[CL], uu[CL];
    #pragma unroll
    for (int i = 0; i < CL; ++i) {
        dt[i] = dp[(size_t)i * DI];
        uu[i] = up[(size_t)i * DI];
    }

    // A row load overlaps with the burst in flight.
    float Av2[DS];
    {
        const float4* Ap = (const float4*)(A + (size_t)d * DS);
        #pragma unroll
        for (int q = 0; q < 4; ++q) {
            const float4 av = Ap[q];
            Av2[q*4+0] = av.x * LOG2E; Av2[q*4+1] = av.y * LOG2E;
            Av2[q*4+2] = av.z * LOG2E; Av2[q*4+3] = av.w * LOG2E;
        }
    }

    // Forward (dt,uu) packed bf16x2 — fire-and-forget stores, coalesced per i.
    {
        unsigned int* __restrict__ fp = dtuu_out + ((size_t)(c * BB + b) * CL) * DI + d;
        #pragma unroll
        for (int i = 0; i < CL; ++i)
            fp[(size_t)i * DI] = pack2(dt[i], uu[i]);
    }

    float Bacc[DS];
    #pragma unroll
    for (int n = 0; n < DS; ++n) Bacc[n] = 0.0f;
    float sdt = 0.0f;

    #pragma unroll
    for (int i = 0; i < CL; ++i) {
        const float du = dt[i] * uu[i];
        sdt += dt[i];
        const float4* bt4 = (const float4*)(bsh + i * DS);   // LDS broadcast
        const float4 b0 = bt4[0], b1 = bt4[1], b2 = bt4[2], b3 = bt4[3];
        const float bv[DS] = {b0.x,b0.y,b0.z,b0.w, b1.x,b1.y,b1.z,b1.w,
                              b2.x,b2.y,b2.z,b2.w, b3.x,b3.y,b3.z,b3.w};
        #pragma unroll
        for (int n = 0; n < DS; ++n) {
            const float a = exp2_fast(dt[i] * Av2[n]);
            Bacc[n] = fmaf(a, Bacc[n], du * bv[n]);
        }
    }

    sdt_out[((size_t)c * BB + b) * DI + d] = sdt;

    uint4* __restrict__ sp = (uint4*)(bsum + (((size_t)c * BB + b) * DI + d) * DS);
    uint4 w0, w1;
    w0.x = pack2(Bacc[0],  Bacc[1]);  w0.y = pack2(Bacc[2],  Bacc[3]);
    w0.z = pack2(Bacc[4],  Bacc[5]);  w0.w = pack2(Bacc[6],  Bacc[7]);
    w1.x = pack2(Bacc[8],  Bacc[9]);  w1.y = pack2(Bacc[10], Bacc[11]);
    w1.z = pack2(Bacc[12], Bacc[13]); w1.w = pack2(Bacc[14], Bacc[15]);
    sp[0] = w0; sp[1] = w1;
}

// ---------------------------------------------------------------------------
// Pass 1.5: exclusive scan over chunks per (b,d,n) chain.
// Prefetch-batched (2 halves of 32). bsum/xin bf16; sdt f32.
// ---------------------------------------------------------------------------
__global__ __launch_bounds__(TPB) void ss_scan(
    const float* __restrict__ A,
    const float* __restrict__ sdt_in, const unsigned short* __restrict__ bsum,
    unsigned short* __restrict__ xin)
{
    const int gid = blockIdx.x * TPB + threadIdx.x;   // (b*DI+d)*DS+n
    const int bd  = gid >> 4;
    const int d   = bd % DI;
    const int n   = gid & 15;
    const float Av2 = A[d * DS + n] * LOG2E;

    const size_t cstr = (size_t)BB * DI * DS;
    const size_t sstr = (size_t)BB * DI;

    float x = 0.0f;
    #pragma unroll
    for (int half = 0; half < 2; ++half) {
        const int c0 = half * 32;
        float sd[32], bs[32];
        #pragma unroll
        for (int j = 0; j < 32; ++j) {
            sd[j] = sdt_in[(size_t)(c0 + j) * sstr + bd];
            bs[j] = __uint_as_float((unsigned int)bsum[(size_t)(c0 + j) * cstr + gid] << 16);
        }
        #pragma unroll
        for (int j = 0; j < 32; ++j) {
            xin[(size_t)(c0 + j) * cstr + gid] = (unsigned short)f2bf_round(x);
            const float a = exp2_fast(Av2 * sd[j]);
            x = fmaf(a, x, bs[j]);
        }
    }
}

// ---------------------------------------------------------------------------
// Pass 2: thread <-> (b, d, chunk). Reads packed (dt,uu) from ws (L2-local,
// half the bytes of re-reading u/delta). Order: stage B/C -> barrier ->
// dtuu burst -> A + xin loads (in flight) -> compute.
// ---------------------------------------------------------------------------
__global__ __launch_bounds__(TPB) void ss2(
    const float* __restrict__ A, const float* __restrict__ Bm,
    const float* __restrict__ Cm, const float* __restrict__ Dv,
    const unsigned int* __restrict__ dtuu,
    const unsigned short* __restrict__ xin, float* __restrict__ y)
{
    __shared__ float bsh[CL * DS];
    __shared__ float csh[CL * DS];

    const int tid = threadIdx.x;
    const int d = blockIdx.x * TPB + tid;
    const int c = blockIdx.y;
    const int b = blockIdx.z;

    const size_t bl0 = (size_t)b * LL + (size_t)c * CL;

    // Stage B and C tiles; barrier drains only these.
    {
        const float* __restrict__ bp0 = Bm + bl0 * DS;
        const float* __restrict__ cp0 = Cm + bl0 * DS;
        if (tid < CL * DS) {
            bsh[tid] = bp0[tid];
            csh[tid] = cp0[tid];
        }
    }
    __syncthreads();

    // Packed burst: 16 uint loads (64B/wave... 1KB/wave per row, coalesced).
    const unsigned int* __restrict__ fp = dtuu + ((size_t)(c * BB + b) * CL) * DI + d;
    float dt[CL], uu[CL];
    {
        unsigned int w[CL];
        #pragma unroll
        for (int i = 0; i < CL; ++i) w[i] = fp[(size_t)i * DI];
        #pragma unroll
        for (int i = 0; i < CL; ++i) { dt[i] = bf_lo(w[i]); uu[i] = bf_hi(w[i]); }
    }

    // A, xin, D loads overlap with the burst in flight.
    float Av2[DS];
    {
        const float4* Ap = (const float4*)(A + (size_t)d * DS);
        #pragma unroll
        for (int q = 0; q < 4; ++q) {
            const float4 av = Ap[q];
            Av2[q*4+0] = av.x * LOG2E; Av2[q*4+1] = av.y * LOG2E;
            Av2[q*4+2] = av.z * LOG2E; Av2[q*4+3] = av.w * LOG2E;
        }
    }

    float x[DS];
    {
        const uint4* __restrict__ xp =
            (const uint4*)(xin + (((size_t)c * BB + b) * DI + d) * DS);
        const uint4 w0 = xp[0], w1 = xp[1];
        x[0]  = bf_lo(w0.x); x[1]  = bf_hi(w0.x);
        x[2]  = bf_lo(w0.y); x[3]  = bf_hi(w0.y);
        x[4]  = bf_lo(w0.z); x[5]  = bf_hi(w0.z);
        x[6]  = bf_lo(w0.w); x[7]  = bf_hi(w0.w);
        x[8]  = bf_lo(w1.x); x[9]  = bf_hi(w1.x);
        x[10] = bf_lo(w1.y); x[11] = bf_hi(w1.y);
        x[12] = bf_lo(w1.z); x[13] = bf_hi(w1.z);
        x[14] = bf_lo(w1.w); x[15] = bf_hi(w1.w);
    }

    const float Dd = Dv[d];
    float* __restrict__ yp = y + bl0 * DI + d;

    #pragma unroll
    for (int i = 0; i < CL; ++i) {
        const float du = dt[i] * uu[i];
        const float4* bt4 = (const float4*)(bsh + i * DS);   // LDS broadcast
        const float4* ct4 = (const float4*)(csh + i * DS);
        const float4 b0 = bt4[0], b1 = bt4[1], b2 = bt4[2], b3 = bt4[3];
        const float4 c0 = ct4[0], c1 = ct4[1], c2 = ct4[2], c3 = ct4[3];
        const float bv[DS] = {b0.x,b0.y,b0.z,b0.w, b1.x,b1.y,b1.z,b1.w,
                              b2.x,b2.y,b2.z,b2.w, b3.x,b3.y,b3.z,b3.w};
        const float cv[DS] = {c0.x,c0.y,c0.z,c0.w, c1.x,c1.y,c1.z,c1.w,
                              c2.x,c2.y,c2.z,c2.w, c3.x,c3.y,c3.z,c3.w};
        float y0 = 0.0f, y1 = 0.0f;
        #pragma unroll
        for (int n = 0; n < DS; ++n) {
            const float a = exp2_fast(dt[i] * Av2[n]);
            x[n] = fmaf(a, x[n], du * bv[n]);
            if (n & 1) y1 = fmaf(x[n], cv[n], y1);
            else       y0 = fmaf(x[n], cv[n], y0);
        }
        yp[(size_t)i * DI] = fmaf(uu[i], Dd, y0 + y1);
    }
}

// Fallback: streaming serial scan (no workspace needed)
__global__ __launch_bounds__(TPB) void ss_serial(
    const float* __restrict__ u, const float* __restrict__ delta,
    const float* __restrict__ A, const float* __restrict__ Bm,
    const float* __restrict__ Cm, const float* __restrict__ Dv,
    float* __restrict__ y)
{
    const int d = blockIdx.x * TPB + threadIdx.x;
    const int b = blockIdx.z;

    float Av2[DS];
    #pragma unroll
    for (int n = 0; n < DS; ++n) Av2[n] = A[d * DS + n] * LOG2E;

    float x[DS];
    #pragma unroll
    for (int n = 0; n < DS; ++n) x[n] = 0.0f;

    const float Dd = Dv[d];
    const size_t bl0 = (size_t)b * LL;
    const float* __restrict__ dp = delta + bl0 * DI + d;
    const float* __restrict__ up = u     + bl0 * DI + d;
    const float* __restrict__ bp = Bm    + bl0 * DS;
    const float* __restrict__ cp = Cm    + bl0 * DS;
    float* __restrict__ yp       = y     + bl0 * DI + d;

    for (int t = 0; t < LL; ++t) {
        const float dtv = dp[(size_t)t * DI];
        const float uuv = up[(size_t)t * DI];
        const float du = dtv * uuv;
        const float* __restrict__ bt = bp + t * DS;
        const float* __restrict__ ct = cp + t * DS;
        float y0 = 0.0f, y1 = 0.0f;
        #pragma unroll
        for (int n = 0; n < DS; ++n) {
            const float a = exp2_fast(dtv * Av2[n]);
            x[n] = fmaf(a, x[n], du * bt[n]);
            if (n & 1) y1 = fmaf(x[n], ct[n], y1);
            else       y0 = fmaf(x[n], ct[n], y0);
        }
        yp[(size_t)t * DI] = fmaf(uuv, Dd, y0 + y1);
    }
}

extern "C" void kernel_launch(void* const* d_in, const int* in_sizes, int n_in,
                              void* d_out, int out_size, void* d_ws, size_t ws_size,
                              hipStream_t stream) {
    const float* u     = (const float*)d_in[0];
    const float* delta = (const float*)d_in[1];
    const float* A     = (const float*)d_in[2];
    const float* Bm    = (const float*)d_in[3];
    const float* Cm    = (const float*)d_in[4];
    const float* Dv    = (const float*)d_in[5];
    float* y = (float*)d_out;

    const size_t sdt_bytes  = (size_t)NC * BB * DI * sizeof(float);               // 0.79 MB
    const size_t bsum_bytes = (size_t)NC * BB * DI * DS * sizeof(unsigned short); // 6.3 MB
    const size_t xin_bytes  = bsum_bytes;                                         // 6.3 MB
    const size_t dtuu_bytes = (size_t)BB * LL * DI * sizeof(unsigned int);        // 12.6 MB

    if (ws_size >= sdt_bytes + bsum_bytes + xin_bytes + dtuu_bytes) {
        char* p = (char*)d_ws;
        float*          sdt  = (float*)p;                 p += sdt_bytes;
        unsigned short* bsum = (unsigned short*)p;        p += bsum_bytes;
        unsigned short* xin  = (unsigned short*)p;        p += xin_bytes;
        unsigned int*   dtuu = (unsigned int*)p;

        dim3 grid1(DI / TPB, NC, BB);
        ss1<<<grid1, TPB, 0, stream>>>(u, delta, A, Bm, sdt, bsum, dtuu);

        dim3 gridS((BB * DI * DS) / TPB, 1, 1);
        ss_scan<<<gridS, TPB, 0, stream>>>(A, sdt, bsum, xin);

        ss2<<<grid1, TPB, 0, stream>>>(A, Bm, Cm, Dv, dtuu, xin, y);
    } else {
        dim3 grid(DI / TPB, 1, BB);
        ss_serial<<<grid, TPB, 0, stream>>>(u, delta, A, Bm, Cm, Dv, y);
    }
}

// Round 18
// 34.722 us; speedup vs baseline: 1.0915x; 1.0915x over previous
//
#include <hip/hip_runtime.h>

// Problem dims (fixed by the reference)
#define BB 2
#define LL 1024
#define DI 1536
#define DS 16
#define TPB 256
#define NC 64
#define CL (LL / NC)   // 16

#define LOG2E 1.44269504088896340736f

__device__ __forceinline__ float exp2_fast(float x) { return __builtin_amdgcn_exp2f(x); }

// bf16 pack/unpack (RNE rounding)
__device__ __forceinline__ unsigned int f2bf_round(float f) {
    unsigned int u = __float_as_uint(f);
    return (u + 0x7FFFu + ((u >> 16) & 1u)) >> 16;
}
__device__ __forceinline__ unsigned int pack2(float lo, float hi) {
    return f2bf_round(lo) | (f2bf_round(hi) << 16);
}
__device__ __forceinline__ float bf_lo(unsigned int w) { return __uint_as_float(w << 16); }
__device__ __forceinline__ float bf_hi(unsigned int w) { return __uint_as_float(w & 0xFFFF0000u); }

// ---------------------------------------------------------------------------
// Pass 1: thread <-> (b, d, chunk); all 16 n-states in registers.
// Order: stage B -> barrier (drains only stage) -> dt/uu burst -> A load
// (in flight with burst) -> compute with per-use waits.
// Stores per-chunk: sdt (f32) and Bacc[16] packed bf16 (2x uint4).
//   x_after = exp2(Av2[n]*sdt)*x_before + Bacc[n]
// Layouts: sdt [c][b][d] f32, bsum [c][b][d][n] bf16 (n-minor)
// ---------------------------------------------------------------------------
__global__ __launch_bounds__(TPB) void ss1(
    const float* __restrict__ u, const float* __restrict__ delta,
    const float* __restrict__ A, const float* __restrict__ Bm,
    float* __restrict__ sdt_out, unsigned short* __restrict__ bsum)
{
    __shared__ float bsh[CL * DS];

    const int tid = threadIdx.x;
    const int d = blockIdx.x * TPB + tid;
    const int c = blockIdx.y;
    const int b = blockIdx.z;

    const size_t bl0 = (size_t)b * LL + (size_t)c * CL;

    // Stage B tile (256 floats, one coalesced load), then barrier that only
    // has to drain this one op — NOT the main burst.
    {
        const float* __restrict__ bp0 = Bm + bl0 * DS;
        if (tid < CL * DS) bsh[tid] = bp0[tid];
    }
    __syncthreads();

    // Issue the 32-load dt/uu burst; compute can start per-use.
    const float* __restrict__ dp = delta + bl0 * DI + d;
    const float* __restrict__ up = u     + bl0 * DI + d;

    float dt[CL], uu[CL];
    #pragma unroll
    for (int i = 0; i < CL; ++i) {
        dt[i] = dp[(size_t)i * DI];          // coalesced 256B/wave
        uu[i] = up[(size_t)i * DI];
    }

    // A row load overlaps with the burst in flight.
    float Av2[DS];
    {
        const float4* Ap = (const float4*)(A + (size_t)d * DS);
        #pragma unroll
        for (int q = 0; q < 4; ++q) {
            const float4 av = Ap[q];
            Av2[q*4+0] = av.x * LOG2E; Av2[q*4+1] = av.y * LOG2E;
            Av2[q*4+2] = av.z * LOG2E; Av2[q*4+3] = av.w * LOG2E;
        }
    }

    float Bacc[DS];
    #pragma unroll
    for (int n = 0; n < DS; ++n) Bacc[n] = 0.0f;
    float sdt = 0.0f;

    #pragma unroll
    for (int i = 0; i < CL; ++i) {
        const float du = dt[i] * uu[i];
        sdt += dt[i];
        const float4* bt4 = (const float4*)(bsh + i * DS);   // LDS broadcast
        const float4 b0 = bt4[0], b1 = bt4[1], b2 = bt4[2], b3 = bt4[3];
        const float bv[DS] = {b0.x,b0.y,b0.z,b0.w, b1.x,b1.y,b1.z,b1.w,
                              b2.x,b2.y,b2.z,b2.w, b3.x,b3.y,b3.z,b3.w};
        #pragma unroll
        for (int n = 0; n < DS; ++n) {
            const float a = exp2_fast(dt[i] * Av2[n]);
            Bacc[n] = fmaf(a, Bacc[n], du * bv[n]);
        }
    }

    sdt_out[((size_t)c * BB + b) * DI + d] = sdt;

    // Pack 16 bf16 into 2x uint4 and store (32B per thread, coalesced)
    uint4* __restrict__ sp = (uint4*)(bsum + (((size_t)c * BB + b) * DI + d) * DS);
    uint4 w0, w1;
    w0.x = pack2(Bacc[0],  Bacc[1]);  w0.y = pack2(Bacc[2],  Bacc[3]);
    w0.z = pack2(Bacc[4],  Bacc[5]);  w0.w = pack2(Bacc[6],  Bacc[7]);
    w1.x = pack2(Bacc[8],  Bacc[9]);  w1.y = pack2(Bacc[10], Bacc[11]);
    w1.z = pack2(Bacc[12], Bacc[13]); w1.w = pack2(Bacc[14], Bacc[15]);
    sp[0] = w0; sp[1] = w1;
}

// ---------------------------------------------------------------------------
// Pass 1.5: exclusive scan over chunks per (b,d,n) chain.
// Prefetch-batched (2 halves of 32): independent loads up-front, then fold.
// bsum/xin in bf16; sdt f32.
// ---------------------------------------------------------------------------
__global__ __launch_bounds__(TPB) void ss_scan(
    const float* __restrict__ A,
    const float* __restrict__ sdt_in, const unsigned short* __restrict__ bsum,
    unsigned short* __restrict__ xin)
{
    const int gid = blockIdx.x * TPB + threadIdx.x;   // (b*DI+d)*DS+n
    const int bd  = gid >> 4;
    const int d   = bd % DI;
    const int n   = gid & 15;
    const float Av2 = A[d * DS + n] * LOG2E;

    const size_t cstr = (size_t)BB * DI * DS;
    const size_t sstr = (size_t)BB * DI;

    float x = 0.0f;
    #pragma unroll
    for (int half = 0; half < 2; ++half) {
        const int c0 = half * 32;
        float sd[32], bs[32];
        #pragma unroll
        for (int j = 0; j < 32; ++j) {
            sd[j] = sdt_in[(size_t)(c0 + j) * sstr + bd];
            bs[j] = __uint_as_float((unsigned int)bsum[(size_t)(c0 + j) * cstr + gid] << 16);
        }
        #pragma unroll
        for (int j = 0; j < 32; ++j) {
            xin[(size_t)(c0 + j) * cstr + gid] = (unsigned short)f2bf_round(x);
            const float a = exp2_fast(Av2 * sd[j]);
            x = fmaf(a, x, bs[j]);
        }
    }
}

// ---------------------------------------------------------------------------
// Pass 2: thread <-> (b, d, chunk). Order: stage B/C -> barrier -> dt/uu
// burst -> A + xin loads (in flight) -> compute with per-use waits.
// ---------------------------------------------------------------------------
__global__ __launch_bounds__(TPB) void ss2(
    const float* __restrict__ u, const float* __restrict__ delta,
    const float* __restrict__ A, const float* __restrict__ Bm,
    const float* __restrict__ Cm, const float* __restrict__ Dv,
    const unsigned short* __restrict__ xin, float* __restrict__ y)
{
    __shared__ float bsh[CL * DS];
    __shared__ float csh[CL * DS];

    const int tid = threadIdx.x;
    const int d = blockIdx.x * TPB + tid;
    const int c = blockIdx.y;
    const int b = blockIdx.z;

    const size_t bl0 = (size_t)b * LL + (size_t)c * CL;

    // Stage B and C tiles; barrier drains only these two ops.
    {
        const float* __restrict__ bp0 = Bm + bl0 * DS;
        const float* __restrict__ cp0 = Cm + bl0 * DS;
        if (tid < CL * DS) {
            bsh[tid] = bp0[tid];
            csh[tid] = cp0[tid];
        }
    }
    __syncthreads();

    // Main burst first — pipelines into the compute loop.
    const float* __restrict__ dp = delta + bl0 * DI + d;
    const float* __restrict__ up = u     + bl0 * DI + d;

    float dt[CL], uu[CL];
    #pragma unroll
    for (int i = 0; i < CL; ++i) {
        dt[i] = dp[(size_t)i * DI];
        uu[i] = up[(size_t)i * DI];
    }

    // A, xin, D loads overlap with the burst in flight.
    float Av2[DS];
    {
        const float4* Ap = (const float4*)(A + (size_t)d * DS);
        #pragma unroll
        for (int q = 0; q < 4; ++q) {
            const float4 av = Ap[q];
            Av2[q*4+0] = av.x * LOG2E; Av2[q*4+1] = av.y * LOG2E;
            Av2[q*4+2] = av.z * LOG2E; Av2[q*4+3] = av.w * LOG2E;
        }
    }

    float x[DS];
    {
        const uint4* __restrict__ xp =
            (const uint4*)(xin + (((size_t)c * BB + b) * DI + d) * DS);
        const uint4 w0 = xp[0], w1 = xp[1];
        x[0]  = bf_lo(w0.x); x[1]  = bf_hi(w0.x);
        x[2]  = bf_lo(w0.y); x[3]  = bf_hi(w0.y);
        x[4]  = bf_lo(w0.z); x[5]  = bf_hi(w0.z);
        x[6]  = bf_lo(w0.w); x[7]  = bf_hi(w0.w);
        x[8]  = bf_lo(w1.x); x[9]  = bf_hi(w1.x);
        x[10] = bf_lo(w1.y); x[11] = bf_hi(w1.y);
        x[12] = bf_lo(w1.z); x[13] = bf_hi(w1.z);
        x[14] = bf_lo(w1.w); x[15] = bf_hi(w1.w);
    }

    const float Dd = Dv[d];
    float* __restrict__ yp = y + bl0 * DI + d;

    #pragma unroll
    for (int i = 0; i < CL; ++i) {
        const float du = dt[i] * uu[i];
        const float4* bt4 = (const float4*)(bsh + i * DS);   // LDS broadcast
        const float4* ct4 = (const float4*)(csh + i * DS);
        const float4 b0 = bt4[0], b1 = bt4[1], b2 = bt4[2], b3 = bt4[3];
        const float4 c0 = ct4[0], c1 = ct4[1], c2 = ct4[2], c3 = ct4[3];
        const float bv[DS] = {b0.x,b0.y,b0.z,b0.w, b1.x,b1.y,b1.z,b1.w,
                              b2.x,b2.y,b2.z,b2.w, b3.x,b3.y,b3.z,b3.w};
        const float cv[DS] = {c0.x,c0.y,c0.z,c0.w, c1.x,c1.y,c1.z,c1.w,
                              c2.x,c2.y,c2.z,c2.w, c3.x,c3.y,c3.z,c3.w};
        float y0 = 0.0f, y1 = 0.0f;
        #pragma unroll
        for (int n = 0; n < DS; ++n) {
            const float a = exp2_fast(dt[i] * Av2[n]);
            x[n] = fmaf(a, x[n], du * bv[n]);
            if (n & 1) y1 = fmaf(x[n], cv[n], y1);
            else       y0 = fmaf(x[n], cv[n], y0);
        }
        yp[(size_t)i * DI] = fmaf(uu[i], Dd, y0 + y1);
    }
}

// Fallback: streaming serial scan (no workspace needed)
__global__ __launch_bounds__(TPB) void ss_serial(
    const float* __restrict__ u, const float* __restrict__ delta,
    const float* __restrict__ A, const float* __restrict__ Bm,
    const float* __restrict__ Cm, const float* __restrict__ Dv,
    float* __restrict__ y)
{
    const int d = blockIdx.x * TPB + threadIdx.x;
    const int b = blockIdx.z;

    float Av2[DS];
    #pragma unroll
    for (int n = 0; n < DS; ++n) Av2[n] = A[d * DS + n] * LOG2E;

    float x[DS];
    #pragma unroll
    for (int n = 0; n < DS; ++n) x[n] = 0.0f;

    const float Dd = Dv[d];
    const size_t bl0 = (size_t)b * LL;
    const float* __restrict__ dp = delta + bl0 * DI + d;
    const float* __restrict__ up = u     + bl0 * DI + d;
    const float* __restrict__ bp = Bm    + bl0 * DS;
    const float* __restrict__ cp = Cm    + bl0 * DS;
    float* __restrict__ yp       = y     + bl0 * DI + d;

    for (int t = 0; t < LL; ++t) {
        const float dtv = dp[(size_t)t * DI];
        const float uuv = up[(size_t)t * DI];
        const float du = dtv * uuv;
        const float* __restrict__ bt = bp + t * DS;
        const float* __restrict__ ct = cp + t * DS;
        float y0 = 0.0f, y1 = 0.0f;
        #pragma unroll
        for (int n = 0; n < DS; ++n) {
            const float a = exp2_fast(dtv * Av2[n]);
            x[n] = fmaf(a, x[n], du * bt[n]);
            if (n & 1) y1 = fmaf(x[n], ct[n], y1);
            else       y0 = fmaf(x[n], ct[n], y0);
        }
        yp[(size_t)t * DI] = fmaf(uuv, Dd, y0 + y1);
    }
}

extern "C" void kernel_launch(void* const* d_in, const int* in_sizes, int n_in,
                              void* d_out, int out_size, void* d_ws, size_t ws_size,
                              hipStream_t stream) {
    const float* u     = (const float*)d_in[0];
    const float* delta = (const float*)d_in[1];
    const float* A     = (const float*)d_in[2];
    const float* Bm    = (const float*)d_in[3];
    const float* Cm    = (const float*)d_in[4];
    const float* Dv    = (const float*)d_in[5];
    float* y = (float*)d_out;

    const size_t sdt_bytes  = (size_t)NC * BB * DI * sizeof(float);               // 0.79 MB
    const size_t bsum_bytes = (size_t)NC * BB * DI * DS * sizeof(unsigned short); // 6.3 MB

    if (ws_size >= sdt_bytes + 2 * bsum_bytes) {
        float* sdt = (float*)d_ws;
        unsigned short* bsum = (unsigned short*)((char*)d_ws + sdt_bytes);
        unsigned short* xin  = (unsigned short*)((char*)d_ws + sdt_bytes + bsum_bytes);

        dim3 grid1(DI / TPB, NC, BB);
        ss1<<<grid1, TPB, 0, stream>>>(u, delta, A, Bm, sdt, bsum);

        dim3 gridS((BB * DI * DS) / TPB, 1, 1);
        ss_scan<<<gridS, TPB, 0, stream>>>(A, sdt, bsum, xin);

        ss2<<<grid1, TPB, 0, stream>>>(u, delta, A, Bm, Cm, Dv, xin, y);
    } else {
        dim3 grid(DI / TPB, 1, BB);
        ss_serial<<<grid, TPB, 0, stream>>>(u, delta, A, Bm, Cm, Dv, y);
    }
}